// Round 7
// baseline (453.413 us; speedup 1.0000x reference)
//
#include <hip/hip_runtime.h>
#include <cfloat>
#include <cstdint>

// ---------------- problem constants ----------------
#define B_BATCH 32
#define D_DIM   256
#define HW      1024
#define N_POS   32768
#define K_CODES 1024
#define DECAY_F   0.99f
#define ONE_M_DECAY 0.01f
#define EPS_F   1e-5f

// ---------------- output layout (floats) ----------------
#define OUT_Q    0                         // 8388608  quantized_st (B,C,H,W)
#define OUT_LOSS 8388608                   // 1
#define OUT_PERP 8388609                   // 1
#define OUT_CB   8388610                   // 262144   new_codebook
#define OUT_NCS  8650754                   // 1024     new_cluster_size
#define OUT_EDW  8651778                   // 262144   new_ema_dw (dw scratch first)

// OUT_Q region doubles as z bf16 hi/lo scratch (exactly 33,554,432 bytes):
// prep writes zhi (16 MB) + zlo (16 MB); argmin + dw read them;
// tail overwrites the region with the real output at the end.

// ---------------- workspace layout (bytes) ----------------
#define WS_COUNTS  0          // 1024*4
#define WS_ZNORM   4096       // 4   (sum ||z||^2)
#define WS_BSUM    4100       // 4   (sum best distances)
#define WS_DONE    4104       // 4   (grid-last ticket)
#define WS_NTOT    4108       // 4
#define WS_TICKET  4112       // 256*4 (per-position-tile tickets)
#define WS_MEMSET  5136       // bytes zeroed at launch
#define WS_CBNORM  5376       // 1024*4
#define WS_OFFS    9472       // 1024*4 (int)
#define WS_CURSOR  13568      // 1024*4 (int)
#define WS_IDX     17664      // 32768*4 (int)
#define WS_SORTED  148736     // 32768*4 (int)
#define WS_CBHI    279808     // 262144*2
#define WS_CBLO    804096     // 262144*2
#define WS_PART    1328384    // 32768*8*8 (u64 partial keys)
#define WS_SCODE   3425536    // 32768*4 (int)
#define WS_TOTAL   3556608

typedef short s16x8 __attribute__((ext_vector_type(8)));
typedef float f32x4 __attribute__((ext_vector_type(4)));
typedef unsigned long long u64;

__device__ __forceinline__ ushort f2bf_rne(float x) {
    uint u = __float_as_uint(x);
    uint r = (u + 0x7FFF + ((u >> 16) & 1)) >> 16;
    return (ushort)r;
}
__device__ __forceinline__ float bf2f(ushort h) {
    return __uint_as_float(((uint)h) << 16);
}

// async global->LDS, 16 B per lane; LDS dst = wave-uniform base + lane*16
__device__ __forceinline__ void gload16(const void* g, void* l) {
    __builtin_amdgcn_global_load_lds(
        (const __attribute__((address_space(1))) unsigned*)(uintptr_t)g,
        (__attribute__((address_space(3))) unsigned*)(uintptr_t)l, 16, 0, 0);
}

// ============================================================
// prep_ztrans: fused.
//  blocks [0,512):  z (d-major) -> zhi/zlo bf16 (position-major) + sum ||z||^2
//  blocks [512,768): codebook fp32 -> bf16 hi/lo + row norms
__global__ __launch_bounds__(256) void prep_ztrans(const float* __restrict__ z,
                                                   const float* __restrict__ cb,
                                                   ushort* __restrict__ zhi,
                                                   ushort* __restrict__ zlo,
                                                   ushort* __restrict__ cbhi,
                                                   ushort* __restrict__ cblo,
                                                   float* __restrict__ cbnorm,
                                                   float* __restrict__ znorm_acc) {
    __shared__ float Zs[32][65];
    __shared__ float red[256];
    const int tid = threadIdx.x;

    if (blockIdx.x >= 512) {   // ---- codebook prep ----
        int wave = tid >> 6;
        int lane = tid & 63;
        int k = (blockIdx.x - 512) * 4 + wave;
        float4 v = *(const float4*)&cb[(size_t)k * D_DIM + lane * 4];
        ushort4 h, l;
        h.x = f2bf_rne(v.x); l.x = f2bf_rne(v.x - bf2f(h.x));
        h.y = f2bf_rne(v.y); l.y = f2bf_rne(v.y - bf2f(h.y));
        h.z = f2bf_rne(v.z); l.z = f2bf_rne(v.z - bf2f(h.z));
        h.w = f2bf_rne(v.w); l.w = f2bf_rne(v.w - bf2f(h.w));
        *(ushort4*)&cbhi[(size_t)k * D_DIM + lane * 4] = h;
        *(ushort4*)&cblo[(size_t)k * D_DIM + lane * 4] = l;
        float s = v.x * v.x + v.y * v.y + v.z * v.z + v.w * v.w;
        #pragma unroll
        for (int off = 32; off >= 1; off >>= 1) s += __shfl_xor(s, off);
        if (lane == 0) cbnorm[k] = s;
        return;
    }

    // ---- z transpose + split ----
    const int n0  = blockIdx.x * 64;
    const int b   = n0 >> 10;
    const int hw0 = n0 & 1023;
    const float* zb = z + (size_t)b * (D_DIM * HW) + hw0;

    const int zn = tid & 63;
    const int zdb = (tid >> 6) * 8;
    const int n  = tid >> 2;
    const int dq = tid & 3;
    float zsum = 0.f;

    for (int d0 = 0; d0 < D_DIM; d0 += 32) {
        __syncthreads();
        #pragma unroll
        for (int j = 0; j < 8; ++j)
            Zs[zdb + j][zn] = zb[(size_t)(d0 + zdb + j) * HW + zn];
        __syncthreads();
        s16x8 hv, lv;
        #pragma unroll
        for (int j = 0; j < 8; ++j) {
            float f = Zs[dq * 8 + j][n];
            zsum += f * f;
            ushort hb = f2bf_rne(f);
            ushort lb = f2bf_rne(f - bf2f(hb));
            hv[j] = (short)hb;
            lv[j] = (short)lb;
        }
        *(s16x8*)&zhi[(size_t)(n0 + n) * D_DIM + d0 + dq * 8] = hv;
        *(s16x8*)&zlo[(size_t)(n0 + n) * D_DIM + d0 + dq * 8] = lv;
    }
    red[tid] = zsum;
    __syncthreads();
    for (int s2 = 128; s2 >= 1; s2 >>= 1) {
        if (tid < s2) red[tid] += red[tid + s2];
        __syncthreads();
    }
    if (tid == 0) atomicAdd(znorm_acc, red[0]);
}

// ============================================================
// argmin_gemm: 128 pos x 128 codes per block, 3-term bf16 MFMA, XCD swizzle.
// FUSED EPILOGUE: last block per position-tile combines the 8 partials
// (idx, counts histogram, bsum); grid-last block runs the stats pass
// (scan -> offsets/cursor, ncs, perplexity, loss, ntot).
__global__ __launch_bounds__(256) void argmin_gemm(const ushort* __restrict__ cbhi,
                                                   const ushort* __restrict__ cblo,
                                                   const ushort* __restrict__ zhi,
                                                   const ushort* __restrict__ zlo,
                                                   const float* __restrict__ cbnorm,
                                                   u64* __restrict__ partial,
                                                   int* __restrict__ ticket,
                                                   int* __restrict__ done_ctr,
                                                   int* __restrict__ idx,
                                                   float* __restrict__ counts,
                                                   float* __restrict__ bsum_acc,
                                                   const float* __restrict__ znorm,
                                                   const float* __restrict__ ema_cs,
                                                   float* __restrict__ out_ncs,
                                                   float* __restrict__ out_perp,
                                                   float* __restrict__ out_loss,
                                                   float* __restrict__ ntot_ws,
                                                   int* __restrict__ offsets,
                                                   int* __restrict__ cursor) {
    __shared__ ushort lds[16384];      // Ahi|Alo|Bhi|Blo, 4096 shorts each
    __shared__ u64 kred[128][2];
    __shared__ int s_last, s_vlast;

    const int tid  = threadIdx.x;
    const int wave = tid >> 6;
    const int lane = tid & 63;
    const int col  = lane & 15;
    const int lg   = lane >> 4;
    const int blk = blockIdx.x;
    const int mt = (blk >> 3) & 7;                       // code tile
    const int pt = (blk & 7) | ((blk >> 6) << 3);        // position tile
    const int ch = wave & 1;
    const int ph = wave >> 1;

    const int r0  = tid >> 2;
    const int dch = (tid & 3) ^ ((r0 >> 1) & 3);
    const size_t eA0 = (size_t)(mt * 128 + r0) * D_DIM + dch * 8;
    const size_t eB0 = (size_t)(pt * 128 + r0) * D_DIM + dch * 8;
    const int ldsw = wave * 512;

    const int swz = (lg ^ ((col >> 1) & 3)) * 8;
    const int soffA = (ch * 64 + col) * 32 + swz;
    const int soffB = (ph * 64 + col) * 32 + swz;

    f32x4 acc[4][4];
    #pragma unroll
    for (int mi = 0; mi < 4; ++mi)
        #pragma unroll
        for (int ni = 0; ni < 4; ++ni) acc[mi][ni] = {0.f, 0.f, 0.f, 0.f};

    for (int s8 = 0; s8 < 8; ++s8) {
        const int d0 = s8 * 32;
        __syncthreads();
        gload16(cbhi + eA0 + d0,            &lds[0     + ldsw]);
        gload16(cbhi + eA0 + 64 * 256 + d0, &lds[2048  + ldsw]);
        gload16(cblo + eA0 + d0,            &lds[4096  + ldsw]);
        gload16(cblo + eA0 + 64 * 256 + d0, &lds[6144  + ldsw]);
        gload16(zhi  + eB0 + d0,            &lds[8192  + ldsw]);
        gload16(zhi  + eB0 + 64 * 256 + d0, &lds[10240 + ldsw]);
        gload16(zlo  + eB0 + d0,            &lds[12288 + ldsw]);
        gload16(zlo  + eB0 + 64 * 256 + d0, &lds[14336 + ldsw]);
        __syncthreads();

        s16x8 ah[4], al[4], bh[4], bl[4];
        #pragma unroll
        for (int mi = 0; mi < 4; ++mi) {
            int so = soffA + mi * 512;
            ah[mi] = *(const s16x8*)&lds[so];
            al[mi] = *(const s16x8*)&lds[4096 + so];
        }
        #pragma unroll
        for (int ni = 0; ni < 4; ++ni) {
            int so = soffB + ni * 512;
            bh[ni] = *(const s16x8*)&lds[8192 + so];
            bl[ni] = *(const s16x8*)&lds[12288 + so];
        }
        #pragma unroll
        for (int mi = 0; mi < 4; ++mi)
            #pragma unroll
            for (int ni = 0; ni < 4; ++ni) {
                acc[mi][ni] = __builtin_amdgcn_mfma_f32_16x16x32_bf16(ah[mi], bh[ni], acc[mi][ni], 0, 0, 0);
                acc[mi][ni] = __builtin_amdgcn_mfma_f32_16x16x32_bf16(ah[mi], bl[ni], acc[mi][ni], 0, 0, 0);
                acc[mi][ni] = __builtin_amdgcn_mfma_f32_16x16x32_bf16(al[mi], bh[ni], acc[mi][ni], 0, 0, 0);
            }
    }

    const int kbase = mt * 128 + ch * 64;
    u64 best[4] = {~0ull, ~0ull, ~0ull, ~0ull};
    #pragma unroll
    for (int mi = 0; mi < 4; ++mi) {
        float4 cn = *(const float4*)&cbnorm[kbase + mi * 16 + lg * 4];
        const float* cnp = (const float*)&cn;
        #pragma unroll
        for (int ni = 0; ni < 4; ++ni) {
            #pragma unroll
            for (int r = 0; r < 4; ++r) {
                float dist = cnp[r] - 2.f * acc[mi][ni][r];
                uint ub = __float_as_uint(dist);
                ub = ub ^ (uint)(((int)ub >> 31) | 0x80000000);
                u64 key = ((u64)ub << 32) | (uint)(kbase + mi * 16 + lg * 4 + r);
                if (key < best[ni]) best[ni] = key;
            }
        }
    }
    #pragma unroll
    for (int ni = 0; ni < 4; ++ni) {
        u64 o = __shfl_xor(best[ni], 16); if (o < best[ni]) best[ni] = o;
        o = __shfl_xor(best[ni], 32); if (o < best[ni]) best[ni] = o;
    }
    if (lane < 16) {
        #pragma unroll
        for (int ni = 0; ni < 4; ++ni)
            kred[ph * 64 + ni * 16 + lane][ch] = best[ni];
    }
    __syncthreads();
    if (tid < 128) {
        u64 a = kred[tid][0], b = kred[tid][1];
        partial[(size_t)(pt * 128 + tid) * 8 + mt] = a < b ? a : b;
    }

    // ---------- fused combine (last block of this pt) ----------
    __threadfence();
    __syncthreads();
    if (tid == 0) s_last = (atomicAdd(&ticket[pt], 1) == 7);
    __syncthreads();
    if (!s_last) return;

    __threadfence();   // acquire: see the other 7 blocks' partial stores
    int* hist = (int*)lds;                       // bytes [0, 4096)
    float* redf = (float*)((char*)lds + 4096);   // bytes [4096, 5120)
    for (int j = tid; j < 1024; j += 256) hist[j] = 0;
    __syncthreads();
    float bd = 0.f;
    if (tid < 128) {
        int n = pt * 128 + tid;
        const u64* p = partial + (size_t)n * 8;
        u64 m = p[0];
        #pragma unroll
        for (int j = 1; j < 8; ++j) { u64 v = p[j]; if (v < m) m = v; }
        int k = (int)(m & 1023u);
        idx[n] = k;
        atomicAdd(&hist[k], 1);
        uint ub = (uint)(m >> 32);
        uint u = (ub & 0x80000000u) ? (ub ^ 0x80000000u) : ~ub;
        bd = __uint_as_float(u);
    }
    redf[tid] = bd;
    __syncthreads();
    for (int s2 = 128; s2 >= 1; s2 >>= 1) {
        if (tid < s2) redf[tid] += redf[tid + s2];
        __syncthreads();
    }
    if (tid == 0) atomicAdd(bsum_acc, redf[0]);
    for (int j = tid; j < 1024; j += 256) {
        int c = hist[j];
        if (c) atomicAdd(&counts[j], (float)c);
    }

    // ---------- grid-last: stats / scan ----------
    __threadfence();
    __syncthreads();
    if (tid == 0) s_vlast = (atomicAdd(done_ctr, 1) == 255);
    __syncthreads();
    if (!s_vlast) return;

    __threadfence();
    int*   si = (int*)lds;                        // 256 ints
    float* s1 = (float*)((char*)lds + 4096);      // 256 f
    float* s2 = (float*)((char*)lds + 5120);      // 256 f
    const int base = tid * 4;
    int c4[4];
    int ssum = 0;
    float n1 = 0.f, n2 = 0.f;
    #pragma unroll
    for (int j = 0; j < 4; ++j) {
        float cnt = counts[base + j];
        int ci = (int)cnt;
        c4[j] = ci;
        ssum += ci;
        float ncs = ema_cs[base + j] * DECAY_F + ONE_M_DECAY * cnt;
        out_ncs[base + j] = ncs;
        n1 += ncs;
        float p = cnt / (float)N_POS;
        n2 += p * logf(p + 1e-10f);
    }
    si[tid] = ssum;
    __syncthreads();
    for (int off = 1; off < 256; off <<= 1) {
        int v = (tid >= off) ? si[tid - off] : 0;
        __syncthreads();
        si[tid] += v;
        __syncthreads();
    }
    int run = si[tid] - ssum;
    #pragma unroll
    for (int j = 0; j < 4; ++j) {
        offsets[base + j] = run;
        cursor[base + j] = run;
        run += c4[j];
    }
    s1[tid] = n1;
    s2[tid] = n2;
    __syncthreads();
    for (int st = 128; st >= 1; st >>= 1) {
        if (tid < st) { s1[tid] += s1[tid + st]; s2[tid] += s2[tid + st]; }
        __syncthreads();
    }
    if (tid == 0) {
        ntot_ws[0] = s1[0];
        out_perp[0] = expf(-s2[0]);
        out_loss[0] = 0.25f * (znorm[0] + bsum_acc[0]) / 8388608.0f;
    }
}

// ============================================================
// scatter: block-aggregated bucket sort; also zeroes the dw scratch region.
__global__ __launch_bounds__(256) void scatter_kernel(const int* __restrict__ idx,
                                                      int* __restrict__ cursor,
                                                      int* __restrict__ sorted,
                                                      int* __restrict__ scode,
                                                      float* __restrict__ dw_zero) {
    __shared__ int hist[1024];
    __shared__ int base_s[1024];
    const int tid = threadIdx.x;
    {
        float4 z4 = {0.f, 0.f, 0.f, 0.f};
        size_t e = ((size_t)blockIdx.x * 256 + tid) * 8;
        *(float4*)&dw_zero[e] = z4;
        *(float4*)&dw_zero[e + 4] = z4;
    }
    for (int j = tid; j < 1024; j += 256) hist[j] = 0;
    __syncthreads();
    int n = blockIdx.x * 256 + tid;
    int k = idx[n];
    atomicAdd(&hist[k], 1);
    __syncthreads();
    for (int j = tid; j < 1024; j += 256) {
        int c = hist[j];
        if (c) base_s[j] = atomicAdd(&cursor[j], c);
        hist[j] = 0;
    }
    __syncthreads();
    int rank = atomicAdd(&hist[k], 1);
    int pos = base_s[k] + rank;
    sorted[pos] = n;
    scode[pos] = k;
}

// ============================================================
// dw_chunk: uniform chunks of the SORTED array. Complete segments store
// directly; chunk-spanning runs atomicAdd. dw pre-zeroed by scatter.
#define DW_CHUNK 64
__global__ __launch_bounds__(256) void dw_chunk_kernel(const ushort* __restrict__ zhi,
                                                       const ushort* __restrict__ zlo,
                                                       const int* __restrict__ sorted,
                                                       const int* __restrict__ scode,
                                                       const int* __restrict__ offsets,
                                                       const float* __restrict__ counts,
                                                       float* __restrict__ dw) {
    __shared__ int sid[DW_CHUNK];
    __shared__ int sk[DW_CHUNK];
    const int tid = threadIdx.x;
    const int p0 = blockIdx.x * DW_CHUNK;
    if (tid < DW_CHUNK) {
        sid[tid] = sorted[p0 + tid];
        sk[tid]  = scode[p0 + tid];
    }
    __syncthreads();
    float acc = 0.f;
    int runstart = 0;
    #pragma unroll 4
    for (int i = 0; i < DW_CHUNK; ++i) {
        int id = sid[i];
        float zv = bf2f(zhi[(size_t)id * D_DIM + tid]) + bf2f(zlo[(size_t)id * D_DIM + tid]);
        acc += zv;
        bool end = (i == DW_CHUNK - 1) || (sk[i + 1] != sk[i]);
        if (end) {
            int k = sk[i];
            int off = offsets[k];
            int cnt = (int)counts[k];
            if (p0 + runstart == off && p0 + i == off + cnt - 1)
                dw[(size_t)k * D_DIM + tid] = acc;
            else
                atomicAdd(&dw[(size_t)k * D_DIM + tid], acc);
            acc = 0.f;
            runstart = i + 1;
        }
    }
}

// ============================================================
// tail: fused.
//  blocks [0,1024):     finalize row k: new_ema_dw (in place) + new_codebook
//  blocks [1024,1536):  fuse: gather codebook rows -> outq (d-major)
__global__ __launch_bounds__(256) void tail_kernel(const float* __restrict__ cb,
                                                   const int* __restrict__ idx,
                                                   const float* __restrict__ ema_dw,
                                                   const float* __restrict__ out_ncs,
                                                   const float* __restrict__ ntot_ws,
                                                   float* __restrict__ out_edw,
                                                   float* __restrict__ out_cb,
                                                   float* __restrict__ outq) {
    __shared__ float Qs[32][65];
    __shared__ int kidx[64];
    const int tid = threadIdx.x;

    if (blockIdx.x < 1024) {   // ---- finalize ----
        int k = blockIdx.x;
        float ncs = out_ncs[k];
        float nt = ntot_ws[0];
        float csz = (ncs + EPS_F) / (nt + (float)K_CODES * EPS_F) * nt;
        size_t e = (size_t)k * D_DIM + tid;
        float ed = ema_dw[e] * DECAY_F + ONE_M_DECAY * out_edw[e];
        out_edw[e] = ed;
        out_cb[e] = ed / csz;
        return;
    }

    // ---- fuse: outq = cb[idx] (== zp + (q - zp) within 1 ulp) ----
    const int n0  = (blockIdx.x - 1024) * 64;
    const int b   = n0 >> 10;
    const int hw0 = n0 & 1023;
    float* ob = outq + (size_t)b * (D_DIM * HW) + hw0;

    if (tid < 64) kidx[tid] = idx[n0 + tid];

    for (int d0 = 0; d0 < D_DIM; d0 += 32) {
        __syncthreads();
        #pragma unroll
        for (int h = 0; h < 2; ++h) {
            int s  = tid + 256 * h;
            int n  = s >> 3;
            int dq = s & 7;
            int k  = kidx[n];
            float4 q = *(const float4*)&cb[(size_t)k * D_DIM + d0 + dq * 4];
            Qs[dq * 4 + 0][n] = q.x;
            Qs[dq * 4 + 1][n] = q.y;
            Qs[dq * 4 + 2][n] = q.z;
            Qs[dq * 4 + 3][n] = q.w;
        }
        __syncthreads();
        #pragma unroll
        for (int j = 0; j < 8; ++j) {
            int v = tid + 256 * j;
            int d = v >> 6;
            int n = v & 63;
            ob[(size_t)(d0 + d) * HW + n] = Qs[d][n];
        }
    }
}

// ============================================================
extern "C" void kernel_launch(void* const* d_in, const int* in_sizes, int n_in,
                              void* d_out, int out_size, void* d_ws, size_t ws_size,
                              hipStream_t stream) {
    const float* z       = (const float*)d_in[0];
    const float* cb      = (const float*)d_in[1];
    const float* ema_cs  = (const float*)d_in[2];
    const float* ema_dw  = (const float*)d_in[3];
    float* out = (float*)d_out;

    char* ws = (char*)d_ws;
    float* ws_counts = (float*)(ws + WS_COUNTS);
    float* ws_znorm  = (float*)(ws + WS_ZNORM);
    float* ws_bsum   = (float*)(ws + WS_BSUM);
    int*   ws_done   = (int*)(ws + WS_DONE);
    float* ws_ntot   = (float*)(ws + WS_NTOT);
    int*   ws_ticket = (int*)(ws + WS_TICKET);
    float* ws_cbnorm = (float*)(ws + WS_CBNORM);
    int*   ws_offs   = (int*)(ws + WS_OFFS);
    int*   ws_cursor = (int*)(ws + WS_CURSOR);
    int*   ws_idx    = (int*)(ws + WS_IDX);
    int*   ws_sorted = (int*)(ws + WS_SORTED);
    ushort* ws_cbhi  = (ushort*)(ws + WS_CBHI);
    ushort* ws_cblo  = (ushort*)(ws + WS_CBLO);
    u64*   ws_part   = (u64*)(ws + WS_PART);
    int*   ws_scode  = (int*)(ws + WS_SCODE);

    // zhi/zlo scratch lives in the OUT_Q region (exactly 32 MB)
    ushort* zhi = (ushort*)out;
    ushort* zlo = zhi + 8388608;

    hipMemsetAsync(d_ws, 0, WS_MEMSET, stream);

    prep_ztrans<<<768, 256, 0, stream>>>(z, cb, zhi, zlo, ws_cbhi, ws_cblo,
                                         ws_cbnorm, ws_znorm);
    argmin_gemm<<<2048, 256, 0, stream>>>(ws_cbhi, ws_cblo, zhi, zlo, ws_cbnorm,
                                          ws_part, ws_ticket, ws_done,
                                          ws_idx, ws_counts, ws_bsum, ws_znorm,
                                          ema_cs, out + OUT_NCS, out + OUT_PERP,
                                          out + OUT_LOSS, ws_ntot, ws_offs, ws_cursor);
    scatter_kernel<<<N_POS / 256, 256, 0, stream>>>(ws_idx, ws_cursor, ws_sorted,
                                                    ws_scode, out + OUT_EDW);
    dw_chunk_kernel<<<N_POS / DW_CHUNK, 256, 0, stream>>>(zhi, zlo, ws_sorted, ws_scode,
                                                          ws_offs, ws_counts, out + OUT_EDW);
    tail_kernel<<<1536, 256, 0, stream>>>(cb, ws_idx, ema_dw, out + OUT_NCS, ws_ntot,
                                          out + OUT_EDW, out + OUT_CB, out + OUT_Q);
}

// Round 8
// 214.786 us; speedup vs baseline: 2.1110x; 2.1110x over previous
//
#include <hip/hip_runtime.h>
#include <cfloat>
#include <cstdint>

// ---------------- problem constants ----------------
#define B_BATCH 32
#define D_DIM   256
#define HW      1024
#define N_POS   32768
#define K_CODES 1024
#define DECAY_F   0.99f
#define ONE_M_DECAY 0.01f
#define EPS_F   1e-5f

// ---------------- output layout (floats) ----------------
#define OUT_Q    0                         // 8388608  quantized_st (B,C,H,W)
#define OUT_LOSS 8388608                   // 1
#define OUT_PERP 8388609                   // 1
#define OUT_CB   8388610                   // 262144   new_codebook
#define OUT_NCS  8650754                   // 1024     new_cluster_size
#define OUT_EDW  8651778                   // 262144   new_ema_dw (dw scratch first)

// OUT_Q region doubles as z bf16 hi/lo scratch (exactly 33,554,432 bytes):
// prep writes zhi (16 MB) + zlo (16 MB); argmin + dw read them;
// tail overwrites the region with the real output at the end.

// ---------------- workspace layout (bytes) ----------------
#define WS_COUNTS  0          // 1024*4
#define WS_ZNORM   4096       // 4   (sum ||z||^2)
#define WS_BSUM    4100       // 4   (sum best distances)
#define WS_DONE    4104       // 4   (grid-last ticket for combine)
#define WS_NTOT    4108       // 4
#define WS_MEMSET  4112       // bytes zeroed at launch
#define WS_CBNORM  5376       // 1024*4
#define WS_OFFS    9472       // 1024*4 (int)
#define WS_CURSOR  13568      // 1024*4 (int)
#define WS_IDX     17664      // 32768*4 (int)
#define WS_SORTED  148736     // 32768*4 (int)
#define WS_CBHI    279808     // 262144*2
#define WS_CBLO    804096     // 262144*2
#define WS_PART    1328384    // 32768*8*8 (u64 partial keys)
#define WS_SCODE   3425536    // 32768*4 (int)
#define WS_TOTAL   3556608

typedef short s16x8 __attribute__((ext_vector_type(8)));
typedef float f32x4 __attribute__((ext_vector_type(4)));
typedef unsigned long long u64;

__device__ __forceinline__ ushort f2bf_rne(float x) {
    uint u = __float_as_uint(x);
    uint r = (u + 0x7FFF + ((u >> 16) & 1)) >> 16;
    return (ushort)r;
}
__device__ __forceinline__ float bf2f(ushort h) {
    return __uint_as_float(((uint)h) << 16);
}

// async global->LDS, 16 B per lane; LDS dst = wave-uniform base + lane*16
__device__ __forceinline__ void gload16(const void* g, void* l) {
    __builtin_amdgcn_global_load_lds(
        (const __attribute__((address_space(1))) unsigned*)(uintptr_t)g,
        (__attribute__((address_space(3))) unsigned*)(uintptr_t)l, 16, 0, 0);
}

// ============================================================
// prep_ztrans: fused.
//  blocks [0,512):  z (d-major) -> zhi/zlo bf16 (position-major) + sum ||z||^2
//  blocks [512,768): codebook fp32 -> bf16 hi/lo + row norms
__global__ __launch_bounds__(256) void prep_ztrans(const float* __restrict__ z,
                                                   const float* __restrict__ cb,
                                                   ushort* __restrict__ zhi,
                                                   ushort* __restrict__ zlo,
                                                   ushort* __restrict__ cbhi,
                                                   ushort* __restrict__ cblo,
                                                   float* __restrict__ cbnorm,
                                                   float* __restrict__ znorm_acc) {
    __shared__ float Zs[32][65];
    __shared__ float red[256];
    const int tid = threadIdx.x;

    if (blockIdx.x >= 512) {   // ---- codebook prep ----
        int wave = tid >> 6;
        int lane = tid & 63;
        int k = (blockIdx.x - 512) * 4 + wave;
        float4 v = *(const float4*)&cb[(size_t)k * D_DIM + lane * 4];
        ushort4 h, l;
        h.x = f2bf_rne(v.x); l.x = f2bf_rne(v.x - bf2f(h.x));
        h.y = f2bf_rne(v.y); l.y = f2bf_rne(v.y - bf2f(h.y));
        h.z = f2bf_rne(v.z); l.z = f2bf_rne(v.z - bf2f(h.z));
        h.w = f2bf_rne(v.w); l.w = f2bf_rne(v.w - bf2f(h.w));
        *(ushort4*)&cbhi[(size_t)k * D_DIM + lane * 4] = h;
        *(ushort4*)&cblo[(size_t)k * D_DIM + lane * 4] = l;
        float s = v.x * v.x + v.y * v.y + v.z * v.z + v.w * v.w;
        #pragma unroll
        for (int off = 32; off >= 1; off >>= 1) s += __shfl_xor(s, off);
        if (lane == 0) cbnorm[k] = s;
        return;
    }

    // ---- z transpose + split ----
    const int n0  = blockIdx.x * 64;
    const int b   = n0 >> 10;
    const int hw0 = n0 & 1023;
    const float* zb = z + (size_t)b * (D_DIM * HW) + hw0;

    const int zn = tid & 63;
    const int zdb = (tid >> 6) * 8;
    const int n  = tid >> 2;
    const int dq = tid & 3;
    float zsum = 0.f;

    for (int d0 = 0; d0 < D_DIM; d0 += 32) {
        __syncthreads();
        #pragma unroll
        for (int j = 0; j < 8; ++j)
            Zs[zdb + j][zn] = zb[(size_t)(d0 + zdb + j) * HW + zn];
        __syncthreads();
        s16x8 hv, lv;
        #pragma unroll
        for (int j = 0; j < 8; ++j) {
            float f = Zs[dq * 8 + j][n];
            zsum += f * f;
            ushort hb = f2bf_rne(f);
            ushort lb = f2bf_rne(f - bf2f(hb));
            hv[j] = (short)hb;
            lv[j] = (short)lb;
        }
        *(s16x8*)&zhi[(size_t)(n0 + n) * D_DIM + d0 + dq * 8] = hv;
        *(s16x8*)&zlo[(size_t)(n0 + n) * D_DIM + d0 + dq * 8] = lv;
    }
    red[tid] = zsum;
    __syncthreads();
    for (int s2 = 128; s2 >= 1; s2 >>= 1) {
        if (tid < s2) red[tid] += red[tid + s2];
        __syncthreads();
    }
    if (tid == 0) atomicAdd(znorm_acc, red[0]);
}

// ============================================================
// argmin_gemm: 128 pos x 128 codes per block, 3-term bf16 MFMA, XCD swizzle.
// ROUND-6 BODY — NO FENCES. (Round-7 lesson: device-scope fences in the hot
// MFMA kernel invalidate concurrent blocks' L2 and cost 5x.)
__global__ __launch_bounds__(256) void argmin_gemm(const ushort* __restrict__ cbhi,
                                                   const ushort* __restrict__ cblo,
                                                   const ushort* __restrict__ zhi,
                                                   const ushort* __restrict__ zlo,
                                                   const float* __restrict__ cbnorm,
                                                   u64* __restrict__ partial) {
    __shared__ ushort lds[16384];      // Ahi|Alo|Bhi|Blo, 4096 shorts each
    __shared__ u64 kred[128][2];

    const int tid  = threadIdx.x;
    const int wave = tid >> 6;
    const int lane = tid & 63;
    const int col  = lane & 15;
    const int lg   = lane >> 4;
    const int blk = blockIdx.x;
    const int mt = (blk >> 3) & 7;                       // code tile
    const int pt = (blk & 7) | ((blk >> 6) << 3);        // position tile
    const int ch = wave & 1;
    const int ph = wave >> 1;

    const int r0  = tid >> 2;
    const int dch = (tid & 3) ^ ((r0 >> 1) & 3);
    const size_t eA0 = (size_t)(mt * 128 + r0) * D_DIM + dch * 8;
    const size_t eB0 = (size_t)(pt * 128 + r0) * D_DIM + dch * 8;
    const int ldsw = wave * 512;

    const int swz = (lg ^ ((col >> 1) & 3)) * 8;
    const int soffA = (ch * 64 + col) * 32 + swz;
    const int soffB = (ph * 64 + col) * 32 + swz;

    f32x4 acc[4][4];
    #pragma unroll
    for (int mi = 0; mi < 4; ++mi)
        #pragma unroll
        for (int ni = 0; ni < 4; ++ni) acc[mi][ni] = {0.f, 0.f, 0.f, 0.f};

    for (int s8 = 0; s8 < 8; ++s8) {
        const int d0 = s8 * 32;
        __syncthreads();
        gload16(cbhi + eA0 + d0,            &lds[0     + ldsw]);
        gload16(cbhi + eA0 + 64 * 256 + d0, &lds[2048  + ldsw]);
        gload16(cblo + eA0 + d0,            &lds[4096  + ldsw]);
        gload16(cblo + eA0 + 64 * 256 + d0, &lds[6144  + ldsw]);
        gload16(zhi  + eB0 + d0,            &lds[8192  + ldsw]);
        gload16(zhi  + eB0 + 64 * 256 + d0, &lds[10240 + ldsw]);
        gload16(zlo  + eB0 + d0,            &lds[12288 + ldsw]);
        gload16(zlo  + eB0 + 64 * 256 + d0, &lds[14336 + ldsw]);
        __syncthreads();

        s16x8 ah[4], al[4], bh[4], bl[4];
        #pragma unroll
        for (int mi = 0; mi < 4; ++mi) {
            int so = soffA + mi * 512;
            ah[mi] = *(const s16x8*)&lds[so];
            al[mi] = *(const s16x8*)&lds[4096 + so];
        }
        #pragma unroll
        for (int ni = 0; ni < 4; ++ni) {
            int so = soffB + ni * 512;
            bh[ni] = *(const s16x8*)&lds[8192 + so];
            bl[ni] = *(const s16x8*)&lds[12288 + so];
        }
        #pragma unroll
        for (int mi = 0; mi < 4; ++mi)
            #pragma unroll
            for (int ni = 0; ni < 4; ++ni) {
                acc[mi][ni] = __builtin_amdgcn_mfma_f32_16x16x32_bf16(ah[mi], bh[ni], acc[mi][ni], 0, 0, 0);
                acc[mi][ni] = __builtin_amdgcn_mfma_f32_16x16x32_bf16(ah[mi], bl[ni], acc[mi][ni], 0, 0, 0);
                acc[mi][ni] = __builtin_amdgcn_mfma_f32_16x16x32_bf16(al[mi], bh[ni], acc[mi][ni], 0, 0, 0);
            }
    }

    const int kbase = mt * 128 + ch * 64;
    u64 best[4] = {~0ull, ~0ull, ~0ull, ~0ull};
    #pragma unroll
    for (int mi = 0; mi < 4; ++mi) {
        float4 cn = *(const float4*)&cbnorm[kbase + mi * 16 + lg * 4];
        const float* cnp = (const float*)&cn;
        #pragma unroll
        for (int ni = 0; ni < 4; ++ni) {
            #pragma unroll
            for (int r = 0; r < 4; ++r) {
                float dist = cnp[r] - 2.f * acc[mi][ni][r];
                uint ub = __float_as_uint(dist);
                ub = ub ^ (uint)(((int)ub >> 31) | 0x80000000);
                u64 key = ((u64)ub << 32) | (uint)(kbase + mi * 16 + lg * 4 + r);
                if (key < best[ni]) best[ni] = key;
            }
        }
    }
    #pragma unroll
    for (int ni = 0; ni < 4; ++ni) {
        u64 o = __shfl_xor(best[ni], 16); if (o < best[ni]) best[ni] = o;
        o = __shfl_xor(best[ni], 32); if (o < best[ni]) best[ni] = o;
    }
    if (lane < 16) {
        #pragma unroll
        for (int ni = 0; ni < 4; ++ni)
            kred[ph * 64 + ni * 16 + lane][ch] = best[ni];
    }
    __syncthreads();
    if (tid < 128) {
        u64 a = kred[tid][0], b = kred[tid][1];
        partial[(size_t)(pt * 128 + tid) * 8 + mt] = a < b ? a : b;
    }
}

// ============================================================
// combine: min over 8 code-tile partials -> idx; LDS histogram -> counts;
// bsum for the loss. GRID-LAST block (128 blocks, lightweight — fences are
// cheap here) runs the stats pass: scan -> offsets/cursor, ncs, perplexity,
// loss, ntot.
__global__ __launch_bounds__(256) void combine_kernel(const u64* __restrict__ partial,
                                                      int* __restrict__ idx,
                                                      float* __restrict__ counts,
                                                      float* __restrict__ bsum_acc,
                                                      int* __restrict__ done_ctr,
                                                      const float* __restrict__ znorm,
                                                      const float* __restrict__ ema_cs,
                                                      float* __restrict__ out_ncs,
                                                      float* __restrict__ out_perp,
                                                      float* __restrict__ out_loss,
                                                      float* __restrict__ ntot_ws,
                                                      int* __restrict__ offsets,
                                                      int* __restrict__ cursor) {
    __shared__ int hist[1024];
    __shared__ float red[256];
    __shared__ int s_vlast;
    const int tid = threadIdx.x;
    for (int j = tid; j < 1024; j += 256) hist[j] = 0;
    __syncthreads();
    int n = blockIdx.x * 256 + tid;
    const u64* p = partial + (size_t)n * 8;
    u64 m = p[0];
    #pragma unroll
    for (int j = 1; j < 8; ++j) { u64 v = p[j]; if (v < m) m = v; }
    int k = (int)(m & 1023u);
    idx[n] = k;
    atomicAdd(&hist[k], 1);
    uint ub = (uint)(m >> 32);
    uint u = (ub & 0x80000000u) ? (ub ^ 0x80000000u) : ~ub;
    red[tid] = __uint_as_float(u);
    __syncthreads();
    for (int s2 = 128; s2 >= 1; s2 >>= 1) {
        if (tid < s2) red[tid] += red[tid + s2];
        __syncthreads();
    }
    if (tid == 0) atomicAdd(bsum_acc, red[0]);
    for (int j = tid; j < 1024; j += 256) {
        int c = hist[j];
        if (c) atomicAdd(&counts[j], (float)c);
    }

    // ---------- grid-last: stats / scan ----------
    __threadfence();
    __syncthreads();
    if (tid == 0) s_vlast = (atomicAdd(done_ctr, 1) == 127);
    __syncthreads();
    if (!s_vlast) return;
    __threadfence();   // acquire

    int*   si = hist;                      // reuse LDS
    __shared__ float s1[256];
    __shared__ float s2[256];
    const int base = tid * 4;
    int c4[4];
    int ssum = 0;
    float n1 = 0.f, n2 = 0.f;
    #pragma unroll
    for (int j = 0; j < 4; ++j) {
        float cnt = counts[base + j];
        int ci = (int)cnt;
        c4[j] = ci;
        ssum += ci;
        float ncs = ema_cs[base + j] * DECAY_F + ONE_M_DECAY * cnt;
        out_ncs[base + j] = ncs;
        n1 += ncs;
        float pr = cnt / (float)N_POS;
        n2 += pr * logf(pr + 1e-10f);
    }
    si[tid] = ssum;
    __syncthreads();
    for (int off = 1; off < 256; off <<= 1) {
        int v = (tid >= off) ? si[tid - off] : 0;
        __syncthreads();
        si[tid] += v;
        __syncthreads();
    }
    int run = si[tid] - ssum;
    #pragma unroll
    for (int j = 0; j < 4; ++j) {
        offsets[base + j] = run;
        cursor[base + j] = run;
        run += c4[j];
    }
    s1[tid] = n1;
    s2[tid] = n2;
    __syncthreads();
    for (int st = 128; st >= 1; st >>= 1) {
        if (tid < st) { s1[tid] += s1[tid + st]; s2[tid] += s2[tid + st]; }
        __syncthreads();
    }
    if (tid == 0) {
        ntot_ws[0] = s1[0];
        out_perp[0] = expf(-s2[0]);
        out_loss[0] = 0.25f * (znorm[0] + bsum_acc[0]) / 8388608.0f;
    }
}

// ============================================================
// scatter: block-aggregated bucket sort; also zeroes the dw scratch region.
__global__ __launch_bounds__(256) void scatter_kernel(const int* __restrict__ idx,
                                                      int* __restrict__ cursor,
                                                      int* __restrict__ sorted,
                                                      int* __restrict__ scode,
                                                      float* __restrict__ dw_zero) {
    __shared__ int hist[1024];
    __shared__ int base_s[1024];
    const int tid = threadIdx.x;
    {
        float4 z4 = {0.f, 0.f, 0.f, 0.f};
        size_t e = ((size_t)blockIdx.x * 256 + tid) * 8;
        *(float4*)&dw_zero[e] = z4;
        *(float4*)&dw_zero[e + 4] = z4;
    }
    for (int j = tid; j < 1024; j += 256) hist[j] = 0;
    __syncthreads();
    int n = blockIdx.x * 256 + tid;
    int k = idx[n];
    atomicAdd(&hist[k], 1);
    __syncthreads();
    for (int j = tid; j < 1024; j += 256) {
        int c = hist[j];
        if (c) base_s[j] = atomicAdd(&cursor[j], c);
        hist[j] = 0;
    }
    __syncthreads();
    int rank = atomicAdd(&hist[k], 1);
    int pos = base_s[k] + rank;
    sorted[pos] = n;
    scode[pos] = k;
}

// ============================================================
// dw_chunk: uniform chunks of the SORTED array. Complete segments store
// directly; chunk-spanning runs atomicAdd. dw pre-zeroed by scatter.
#define DW_CHUNK 64
__global__ __launch_bounds__(256) void dw_chunk_kernel(const ushort* __restrict__ zhi,
                                                       const ushort* __restrict__ zlo,
                                                       const int* __restrict__ sorted,
                                                       const int* __restrict__ scode,
                                                       const int* __restrict__ offsets,
                                                       const float* __restrict__ counts,
                                                       float* __restrict__ dw) {
    __shared__ int sid[DW_CHUNK];
    __shared__ int sk[DW_CHUNK];
    const int tid = threadIdx.x;
    const int p0 = blockIdx.x * DW_CHUNK;
    if (tid < DW_CHUNK) {
        sid[tid] = sorted[p0 + tid];
        sk[tid]  = scode[p0 + tid];
    }
    __syncthreads();
    float acc = 0.f;
    int runstart = 0;
    #pragma unroll 4
    for (int i = 0; i < DW_CHUNK; ++i) {
        int id = sid[i];
        float zv = bf2f(zhi[(size_t)id * D_DIM + tid]) + bf2f(zlo[(size_t)id * D_DIM + tid]);
        acc += zv;
        bool end = (i == DW_CHUNK - 1) || (sk[i + 1] != sk[i]);
        if (end) {
            int k = sk[i];
            int off = offsets[k];
            int cnt = (int)counts[k];
            if (p0 + runstart == off && p0 + i == off + cnt - 1)
                dw[(size_t)k * D_DIM + tid] = acc;
            else
                atomicAdd(&dw[(size_t)k * D_DIM + tid], acc);
            acc = 0.f;
            runstart = i + 1;
        }
    }
}

// ============================================================
// tail: fused.
//  blocks [0,1024):     finalize row k: new_ema_dw (in place) + new_codebook
//  blocks [1024,1536):  fuse: gather codebook rows -> outq (d-major)
__global__ __launch_bounds__(256) void tail_kernel(const float* __restrict__ cb,
                                                   const int* __restrict__ idx,
                                                   const float* __restrict__ ema_dw,
                                                   const float* __restrict__ out_ncs,
                                                   const float* __restrict__ ntot_ws,
                                                   float* __restrict__ out_edw,
                                                   float* __restrict__ out_cb,
                                                   float* __restrict__ outq) {
    __shared__ float Qs[32][65];
    __shared__ int kidx[64];
    const int tid = threadIdx.x;

    if (blockIdx.x < 1024) {   // ---- finalize ----
        int k = blockIdx.x;
        float ncs = out_ncs[k];
        float nt = ntot_ws[0];
        float csz = (ncs + EPS_F) / (nt + (float)K_CODES * EPS_F) * nt;
        size_t e = (size_t)k * D_DIM + tid;
        float ed = ema_dw[e] * DECAY_F + ONE_M_DECAY * out_edw[e];
        out_edw[e] = ed;
        out_cb[e] = ed / csz;
        return;
    }

    // ---- fuse: outq = cb[idx] (== zp + (q - zp) within 1 ulp) ----
    const int n0  = (blockIdx.x - 1024) * 64;
    const int b   = n0 >> 10;
    const int hw0 = n0 & 1023;
    float* ob = outq + (size_t)b * (D_DIM * HW) + hw0;

    if (tid < 64) kidx[tid] = idx[n0 + tid];

    for (int d0 = 0; d0 < D_DIM; d0 += 32) {
        __syncthreads();
        #pragma unroll
        for (int h = 0; h < 2; ++h) {
            int s  = tid + 256 * h;
            int n  = s >> 3;
            int dq = s & 7;
            int k  = kidx[n];
            float4 q = *(const float4*)&cb[(size_t)k * D_DIM + d0 + dq * 4];
            Qs[dq * 4 + 0][n] = q.x;
            Qs[dq * 4 + 1][n] = q.y;
            Qs[dq * 4 + 2][n] = q.z;
            Qs[dq * 4 + 3][n] = q.w;
        }
        __syncthreads();
        #pragma unroll
        for (int j = 0; j < 8; ++j) {
            int v = tid + 256 * j;
            int d = v >> 6;
            int n = v & 63;
            ob[(size_t)(d0 + d) * HW + n] = Qs[d][n];
        }
    }
}

// ============================================================
extern "C" void kernel_launch(void* const* d_in, const int* in_sizes, int n_in,
                              void* d_out, int out_size, void* d_ws, size_t ws_size,
                              hipStream_t stream) {
    const float* z       = (const float*)d_in[0];
    const float* cb      = (const float*)d_in[1];
    const float* ema_cs  = (const float*)d_in[2];
    const float* ema_dw  = (const float*)d_in[3];
    float* out = (float*)d_out;

    char* ws = (char*)d_ws;
    float* ws_counts = (float*)(ws + WS_COUNTS);
    float* ws_znorm  = (float*)(ws + WS_ZNORM);
    float* ws_bsum   = (float*)(ws + WS_BSUM);
    int*   ws_done   = (int*)(ws + WS_DONE);
    float* ws_ntot   = (float*)(ws + WS_NTOT);
    float* ws_cbnorm = (float*)(ws + WS_CBNORM);
    int*   ws_offs   = (int*)(ws + WS_OFFS);
    int*   ws_cursor = (int*)(ws + WS_CURSOR);
    int*   ws_idx    = (int*)(ws + WS_IDX);
    int*   ws_sorted = (int*)(ws + WS_SORTED);
    ushort* ws_cbhi  = (ushort*)(ws + WS_CBHI);
    ushort* ws_cblo  = (ushort*)(ws + WS_CBLO);
    u64*   ws_part   = (u64*)(ws + WS_PART);
    int*   ws_scode  = (int*)(ws + WS_SCODE);

    // zhi/zlo scratch lives in the OUT_Q region (exactly 32 MB)
    ushort* zhi = (ushort*)out;
    ushort* zlo = zhi + 8388608;

    hipMemsetAsync(d_ws, 0, WS_MEMSET, stream);

    prep_ztrans<<<768, 256, 0, stream>>>(z, cb, zhi, zlo, ws_cbhi, ws_cblo,
                                         ws_cbnorm, ws_znorm);
    argmin_gemm<<<2048, 256, 0, stream>>>(ws_cbhi, ws_cblo, zhi, zlo, ws_cbnorm, ws_part);
    combine_kernel<<<N_POS / 256, 256, 0, stream>>>(ws_part, ws_idx, ws_counts, ws_bsum,
                                                    ws_done, ws_znorm, ema_cs,
                                                    out + OUT_NCS, out + OUT_PERP,
                                                    out + OUT_LOSS, ws_ntot,
                                                    ws_offs, ws_cursor);
    scatter_kernel<<<N_POS / 256, 256, 0, stream>>>(ws_idx, ws_cursor, ws_sorted,
                                                    ws_scode, out + OUT_EDW);
    dw_chunk_kernel<<<N_POS / DW_CHUNK, 256, 0, stream>>>(zhi, zlo, ws_sorted, ws_scode,
                                                          ws_offs, ws_counts, out + OUT_EDW);
    tail_kernel<<<1536, 256, 0, stream>>>(cb, ws_idx, ema_dw, out + OUT_NCS, ws_ntot,
                                          out + OUT_EDW, out + OUT_CB, out + OUT_Q);
}